// Round 3
// baseline (63.323 us; speedup 1.0000x reference)
//
#include <hip/hip_runtime.h>

namespace {
constexpr int kB   = 2;
constexpr int kC   = 64;
constexpr int kH   = 128;
constexpr int kW   = 240;
constexpr int kD0  = 16;          // disps 0,3,...,45
constexpr int kD1  = 5;           // disps -2,-1,0,1,2
constexpr int kWc1 = 285;
constexpr int kWc2 = 242;
constexpr int kPad = 48;          // >= max disp 45, multiple of 4
constexpr int kHC  = 144;         // output columns per half-block
constexpr int kLRow = 196;        // staged row stride (floats, mult of 4)
constexpr int kLF4  = kLRow / 4;  // 49 float4 per row
constexpr int kThreads = 960;     // 15 waves; 2 blocks/CU (1920 <= 2048 thr)
constexpr int kGT  = 160;         // threads per channel-group (6 groups)
constexpr int kAcc = kD0 + kD1;   // 21
constexpr int kSFl = kC * kLRow;  // 12544 floats = 50176 B LDS
constexpr int kOut1 = kB * kD0 * kH * kWc1;
}

__global__ __launch_bounds__(kThreads)
void anynet_disp_kernel(const float* __restrict__ fr, float* __restrict__ out) {
  __shared__ float S[kSFl];   // phase A/B: staged exp(feat_r); phase C: reduce buf
  const int blk  = blockIdx.x;       // 0..511
  const int half = blk & 1;
  const int bh   = blk >> 1;
  const int b    = bh >> 7;
  const int h    = bh & 127;
  const int colbeg = half * kHC;
  const int tid  = threadIdx.x;

  // ---- phase A: stage exp(feat_r[b,:,h, colbeg-48 .. colbeg+148)) ; out-of-
  // range = 1.0 (= exp(0), the "invalid disparity" cost). Region boundaries
  // are 4-aligned, so each float4 is fully in-range or fully pad.
  const float* fr_bh = fr + (size_t)(b * kC) * (kH * kW) + (size_t)h * kW;
  for (int i = tid; i < kC * kLF4; i += kThreads) {
    const int row = i / kLF4;
    const int lq  = i % kLF4;
    const int x0  = colbeg + 4 * lq - kPad;   // unpadded source x of elem 0
    float4 e;
    if (x0 >= 0 && x0 + 3 < kW) {
      const float4 v =
          *reinterpret_cast<const float4*>(fr_bh + (size_t)row * (kH * kW) + x0);
      e.x = __expf(v.x); e.y = __expf(v.y); e.z = __expf(v.z); e.w = __expf(v.w);
    } else {
      e.x = e.y = e.z = e.w = 1.0f;
    }
    *reinterpret_cast<float4*>(&S[row * kLRow + 4 * lq]) = e;
  }
  __syncthreads();

  // ---- phase B: 6 channel-groups; thread t owns output column colbeg+t
  const int g = tid / kGT;           // 0..5
  const int t = tid % kGT;
  float acc1[kD0] = {};
  float acc2[kD1] = {};
  if (t < kHC) {
    const int cbeg = (g < 4) ? 11 * g : 44 + 10 * (g - 4);
    const int clen = (g < 4) ? 11 : 10;
    const int tb   = t + kPad;       // local padded index; taps in [3,194)
    for (int cc = 0; cc < clen; ++cc) {
      const float* __restrict__ row = &S[(cbeg + cc) * kLRow];
      float v[kD0];
      float s = 0.0f;
      #pragma unroll
      for (int k = 0; k < kD0; ++k) { v[k] = row[tb - 3 * k]; s += v[k]; }
      const float r = __builtin_amdgcn_rcpf(s);
      #pragma unroll
      for (int k = 0; k < kD0; ++k) acc1[k] = fmaf(v[k], r, acc1[k]);

      float u[kD1];
      float s2 = 0.0f;
      #pragma unroll
      for (int j = 0; j < kD1; ++j) { u[j] = row[tb + 2 - j]; s2 += u[j]; }
      const float r2 = __builtin_amdgcn_rcpf(s2);
      #pragma unroll
      for (int j = 0; j < kD1; ++j) acc2[j] = fmaf(u[j], r2, acc2[j]);
    }
  }
  __syncthreads();   // all reads of staged E done; S reusable

  // ---- phase C: combine the 6 group-partials via LDS atomics
  for (int i = tid; i < kHC * kAcc; i += kThreads) S[i] = 0.0f;
  __syncthreads();
  if (t < kHC) {
    float* __restrict__ F = &S[t * kAcc];   // stride 21 (odd) -> conflict-free
    #pragma unroll
    for (int k = 0; k < kD0; ++k) atomicAdd(&F[k], acc1[k]);
    #pragma unroll
    for (int j = 0; j < kD1; ++j) atomicAdd(&F[kD0 + j], acc2[j]);
  }
  __syncthreads();

  // ---- phase D: coalesced global writes
  for (int i = tid; i < kD0 * kHC; i += kThreads) {
    const int d  = i / kHC;
    const int t2 = i % kHC;
    const int col = colbeg + t2;
    if (col < kWc1)
      out[((b * kD0 + d) * kH + h) * kWc1 + col] =
          (3.0f * (float)d) * (4.0f + S[t2 * kAcc + d]);      // C/D0 = 4
  }
  for (int i = tid; i < kD1 * kHC; i += kThreads) {
    const int j  = i / kHC;
    const int t2 = i % kHC;
    const int col = colbeg + t2;
    if (col < kWc2)
      out[kOut1 + ((b * kD1 + j) * kH + h) * kWc2 + col] =
          (float)(j - 2) * (64.0f / 5.0f + S[t2 * kAcc + kD0 + j]);  // C/D1
  }
}

extern "C" void kernel_launch(void* const* d_in, const int* in_sizes, int n_in,
                              void* d_out, int out_size, void* d_ws, size_t ws_size,
                              hipStream_t stream) {
  const float* feat_r = (const float*)d_in[1];  // feats_l contributes exactly C/D
  float* out = (float*)d_out;
  anynet_disp_kernel<<<dim3(kB * kH * 2), dim3(kThreads), 0, stream>>>(feat_r, out);
}

// Round 4
// 19.745 us; speedup vs baseline: 3.2071x; 3.2071x over previous
//
#include <hip/hip_runtime.h>

namespace {
constexpr int kB   = 2;
constexpr int kC   = 64;
constexpr int kH   = 128;
constexpr int kW   = 240;
constexpr int kD0  = 16;          // disps 0,3,...,45
constexpr int kD1  = 5;           // disps -2,-1,0,1,2
constexpr int kWc1 = 285;
constexpr int kWc2 = 242;
constexpr int kPad = 48;          // >= max disp 45, multiple of 4
constexpr int kHC  = 144;         // output columns per half-block
constexpr int kLRow = 196;        // staged row stride (floats, mult of 4)
constexpr int kLF4  = kLRow / 4;  // 49 float4 per row
constexpr int kThreads = 960;     // 15 waves; 2 blocks/CU
constexpr int kGT  = 160;         // threads per channel-group (6 groups)
constexpr int kAcc = kD0 + kD1;   // 21
constexpr int kSlot = kHC * kAcc; // 3024 floats per partial slot (3 slots)
constexpr int kSFl = kC * kLRow;  // 12544 floats = 50176 B LDS
constexpr int kOut1 = kB * kD0 * kH * kWc1;
}

__global__ __launch_bounds__(kThreads, 8)   // cap VGPR at 64 -> 2 blocks/CU
void anynet_disp_kernel(const float* __restrict__ fr, float* __restrict__ out) {
  __shared__ float S[kSFl];   // phase A/B: staged exp(feat_r); phase C: partials
  const int blk  = blockIdx.x;       // 0..511
  const int half = blk & 1;
  const int bh   = blk >> 1;
  const int b    = bh >> 7;
  const int h    = bh & 127;
  const int colbeg = half * kHC;
  const int tid  = threadIdx.x;

  // ---- phase A: stage exp(feat_r[b,:,h, colbeg-48 .. colbeg+148)); OOB = 1.0
  // (= exp(0), "invalid disparity"). Boundaries 4-aligned -> float4 all-or-none.
  const float* fr_bh = fr + (size_t)(b * kC) * (kH * kW) + (size_t)h * kW;
  for (int i = tid; i < kC * kLF4; i += kThreads) {
    const int row = i / kLF4;
    const int lq  = i % kLF4;
    const int x0  = colbeg + 4 * lq - kPad;
    float4 e;
    if (x0 >= 0 && x0 + 3 < kW) {
      const float4 v =
          *reinterpret_cast<const float4*>(fr_bh + (size_t)row * (kH * kW) + x0);
      e.x = __expf(v.x); e.y = __expf(v.y); e.z = __expf(v.z); e.w = __expf(v.w);
    } else {
      e.x = e.y = e.z = e.w = 1.0f;
    }
    *reinterpret_cast<float4*>(&S[row * kLRow + 4 * lq]) = e;
  }
  __syncthreads();

  // ---- phase B: 6 channel-groups; thread t owns output column colbeg+t
  const int g = tid / kGT;           // 0..5
  const int t = tid % kGT;
  float acc1[kD0] = {};
  float acc2[kD1] = {};
  if (t < kHC) {
    const int cbeg = (g < 4) ? 11 * g : 44 + 10 * (g - 4);
    const int clen = (g < 4) ? 11 : 10;
    const int tb   = t + kPad;       // taps within [3,194) of the staged row
    for (int cc = 0; cc < clen; ++cc) {
      const float* __restrict__ row = &S[(cbeg + cc) * kLRow];
      float v[kD0], u[kD1];
      #pragma unroll
      for (int k = 0; k < kD0; ++k) v[k] = row[tb - 3 * k];
      #pragma unroll
      for (int j = 0; j < kD1; ++j) u[j] = row[tb + 2 - j];
      // Force all 21 taps live together: 21 outstanding ds_reads, one waitcnt.
      asm volatile("" : "+v"(v[0]), "+v"(v[1]), "+v"(v[2]), "+v"(v[3]),
                        "+v"(v[4]), "+v"(v[5]), "+v"(v[6]), "+v"(v[7]),
                        "+v"(v[8]), "+v"(v[9]), "+v"(v[10]), "+v"(v[11]),
                        "+v"(v[12]), "+v"(v[13]), "+v"(v[14]), "+v"(v[15]),
                        "+v"(u[0]), "+v"(u[1]), "+v"(u[2]), "+v"(u[3]),
                        "+v"(u[4]));
      // pairwise tree sums (short dependency chain)
      const float a01 = v[0] + v[1],  a23 = v[2] + v[3];
      const float a45 = v[4] + v[5],  a67 = v[6] + v[7];
      const float a89 = v[8] + v[9],  aab = v[10] + v[11];
      const float acd = v[12] + v[13], aef = v[14] + v[15];
      const float s = ((a01 + a23) + (a45 + a67)) + ((a89 + aab) + (acd + aef));
      const float r = __builtin_amdgcn_rcpf(s);
      #pragma unroll
      for (int k = 0; k < kD0; ++k) acc1[k] = fmaf(v[k], r, acc1[k]);
      const float s2 = (u[0] + u[1]) + (u[2] + (u[3] + u[4]));
      const float r2 = __builtin_amdgcn_rcpf(s2);
      #pragma unroll
      for (int j = 0; j < kD1; ++j) acc2[j] = fmaf(u[j], r2, acc2[j]);
    }
  }
  __syncthreads();   // staged E no longer needed; S reusable

  // ---- phase C1: groups 3..5 dump partials (disjoint slots, stride 21)
  if (g >= 3 && t < kHC) {
    float* __restrict__ R = &S[(g - 3) * kSlot + t * kAcc];
    #pragma unroll
    for (int k = 0; k < kD0; ++k) R[k] = acc1[k];
    #pragma unroll
    for (int j = 0; j < kD1; ++j) R[kD0 + j] = acc2[j];
  }
  __syncthreads();
  // ---- phase C2: groups 0..2 add partner partial, write combined back
  if (g < 3 && t < kHC) {
    float* __restrict__ R = &S[g * kSlot + t * kAcc];
    #pragma unroll
    for (int k = 0; k < kD0; ++k) R[k] += acc1[k];
    #pragma unroll
    for (int j = 0; j < kD1; ++j) R[kD0 + j] += acc2[j];
  }
  __syncthreads();

  // ---- phase D: combine 3 slots, coalesced global writes
  for (int i = tid; i < kD0 * kHC; i += kThreads) {
    const int d  = i / kHC;
    const int t2 = i % kHC;
    const int col = colbeg + t2;
    if (col < kWc1) {
      const int o = t2 * kAcc + d;
      const float v = S[o] + S[kSlot + o] + S[2 * kSlot + o];
      out[((b * kD0 + d) * kH + h) * kWc1 + col] =
          (3.0f * (float)d) * (4.0f + v);            // C/D0 = 4
    }
  }
  for (int i = tid; i < kD1 * kHC; i += kThreads) {
    const int j  = i / kHC;
    const int t2 = i % kHC;
    const int col = colbeg + t2;
    if (col < kWc2) {
      const int o = t2 * kAcc + kD0 + j;
      const float v = S[o] + S[kSlot + o] + S[2 * kSlot + o];
      out[kOut1 + ((b * kD1 + j) * kH + h) * kWc2 + col] =
          (float)(j - 2) * (64.0f / 5.0f + v);       // C/D1 = 12.8
    }
  }
}

extern "C" void kernel_launch(void* const* d_in, const int* in_sizes, int n_in,
                              void* d_out, int out_size, void* d_ws, size_t ws_size,
                              hipStream_t stream) {
  const float* feat_r = (const float*)d_in[1];  // feats_l contributes exactly C/D
  float* out = (float*)d_out;
  anynet_disp_kernel<<<dim3(kB * kH * 2), dim3(kThreads), 0, stream>>>(feat_r, out);
}